// Round 1
// baseline (158.470 us; speedup 1.0000x reference)
//
#include <hip/hip_runtime.h>
#include <hip/hip_bf16.h>
#include <math.h>

// Problem constants
#define BATCH   4096
#define DIM     512
#define TWO_B   8192
#define INV_T   10.0f                       // 1/TEMP
#define LSE_SCALE 14.426950408889634f       // log2(e)/TEMP

typedef __attribute__((ext_vector_type(8))) short bf16x8;   // 8 bf16 = 4 VGPRs
typedef __attribute__((ext_vector_type(4))) float floatx4;

#define AS1(p) ((__attribute__((address_space(1))) void*)(p))
#define AS3(p) ((__attribute__((address_space(3))) void*)(p))

// ---------------------------------------------------------------------------
// Kernel 1: L2-normalize pairs (row i of proj_1, row i of proj_2), write bf16
// z[2B][D], and compute positives pos[i] = cos(z_i, z_{i+B})/TEMP in fp32.
// One block of 256 threads per pair; each thread owns 2 columns (float2).
// ---------------------------------------------------------------------------
__global__ __launch_bounds__(256) void norm_kernel(
    const float* __restrict__ p1, const float* __restrict__ p2,
    __hip_bfloat16* __restrict__ z, float* __restrict__ pos)
{
    const int i = blockIdx.x;          // 0..4095
    const int t = threadIdx.x;         // 0..255
    const int wave = t >> 6, lane = t & 63;

    const float2 xv = ((const float2*)(p1 + (size_t)i * DIM))[t];
    const float2 yv = ((const float2*)(p2 + (size_t)i * DIM))[t];

    float sx = fmaf(xv.x, xv.x, xv.y * xv.y);
    float sy = fmaf(yv.x, yv.x, yv.y * yv.y);
    float sd = fmaf(xv.x, yv.x, xv.y * yv.y);

    #pragma unroll
    for (int off = 32; off > 0; off >>= 1) {
        sx += __shfl_down(sx, off);
        sy += __shfl_down(sy, off);
        sd += __shfl_down(sd, off);
    }

    __shared__ float red[3][4];
    if (lane == 0) { red[0][wave] = sx; red[1][wave] = sy; red[2][wave] = sd; }
    __syncthreads();
    sx = red[0][0] + red[0][1] + red[0][2] + red[0][3];
    sy = red[1][0] + red[1][1] + red[1][2] + red[1][3];
    sd = red[2][0] + red[2][1] + red[2][2] + red[2][3];

    const float nx = fmaxf(sqrtf(sx), 1e-12f);
    const float ny = fmaxf(sqrtf(sy), 1e-12f);
    const float rx = 1.0f / nx, ry = 1.0f / ny;

    __hip_bfloat162* zx = (__hip_bfloat162*)(z + (size_t)i * DIM);
    __hip_bfloat162* zy = (__hip_bfloat162*)(z + (size_t)(i + BATCH) * DIM);
    __hip_bfloat162 ax, ay;
    ax.x = __float2bfloat16(xv.x * rx); ax.y = __float2bfloat16(xv.y * rx);
    ay.x = __float2bfloat16(yv.x * ry); ay.y = __float2bfloat16(yv.y * ry);
    zx[t] = ax;
    zy[t] = ay;

    if (t == 0) pos[i] = sd * rx * ry * INV_T;
}

// ---------------------------------------------------------------------------
// Kernel 2: fused z@z^T tile GEMM (bf16 MFMA 16x16x32, 128x128 tile, BK=32,
// global_load_lds width=16 staging — m97 structure) + exp2 epilogue with
// diagonal masking + per-row partial sumexp written to partial[ct][row].
// Grid: (64 col-tiles, 64 row-tiles), 256 threads (4 waves, 2x2 wave grid).
// ---------------------------------------------------------------------------
__global__ __launch_bounds__(256) void sim_kernel(
    const __hip_bfloat16* __restrict__ z, float* __restrict__ partial)
{
    __shared__ __hip_bfloat16 As[128 * 32];    // 8 KB
    __shared__ __hip_bfloat16 Bs[128 * 32];    // 8 KB
    __shared__ float rowred[128][2];           // 1 KB

    const int ct = blockIdx.x;                 // column tile
    const int rt = blockIdx.y;                 // row tile
    const int t = threadIdx.x;
    const int wave = t >> 6, lane = t & 63;
    const int wr = wave >> 1, wc = wave & 1;   // 2x2 wave grid, 64x64 each
    const int quad = lane >> 4, lc = lane & 15;

    const __hip_bfloat16* Ag = z + (size_t)rt * 128 * DIM;
    const __hip_bfloat16* Bg = z + (size_t)ct * 128 * DIM;

    floatx4 acc[4][4];
    #pragma unroll
    for (int mi = 0; mi < 4; ++mi)
        #pragma unroll
        for (int ni = 0; ni < 4; ++ni)
            acc[mi][ni] = (floatx4)0.0f;

    for (int k0 = 0; k0 < DIM; k0 += 32) {
        __syncthreads();   // previous iter's ds_reads done before overwrite
        #pragma unroll
        for (int i = 0; i < 2; ++i) {
            const int e = (i * 256 + t) * 8;   // bf16 element index in tile
            const int r = e >> 5, c = e & 31;  // [128][32] row-major, no pad
            // LDS dest is wave-uniform base + lane*16 (HW rule); element e
            // lands exactly at As[e] because chunk layout matches lane order.
            __builtin_amdgcn_global_load_lds(AS1(Ag + (size_t)r * DIM + k0 + c),
                                             AS3(As + i * 2048 + wave * 512),
                                             16, 0, 0);
            __builtin_amdgcn_global_load_lds(AS1(Bg + (size_t)r * DIM + k0 + c),
                                             AS3(Bs + i * 2048 + wave * 512),
                                             16, 0, 0);
        }
        __syncthreads();

        // A-frag: lane holds A[m=lc][k=quad*8+j]; B-frag mirrors (B^T rows).
        bf16x8 af[4], bf[4];
        #pragma unroll
        for (int mi = 0; mi < 4; ++mi)
            af[mi] = *(const bf16x8*)(As + (wr * 64 + mi * 16 + lc) * 32 + quad * 8);
        #pragma unroll
        for (int ni = 0; ni < 4; ++ni)
            bf[ni] = *(const bf16x8*)(Bs + (wc * 64 + ni * 16 + lc) * 32 + quad * 8);

        #pragma unroll
        for (int mi = 0; mi < 4; ++mi)
            #pragma unroll
            for (int ni = 0; ni < 4; ++ni)
                acc[mi][ni] = __builtin_amdgcn_mfma_f32_16x16x32_bf16(
                    af[mi], bf[ni], acc[mi][ni], 0, 0, 0);
    }

    // Epilogue: exp2(sim * log2e/T), zero the diagonal, per-row partial sums.
    // C/D layout: col = lc, row = quad*4 + reg (within each 16x16 tile).
    float rs[4][4];   // [mi][reg] partial row sums over this wave's 64 cols
    #pragma unroll
    for (int mi = 0; mi < 4; ++mi)
        #pragma unroll
        for (int r = 0; r < 4; ++r)
            rs[mi][r] = 0.0f;

    const bool diag_tile = (rt == ct);
    #pragma unroll
    for (int mi = 0; mi < 4; ++mi) {
        #pragma unroll
        for (int r = 0; r < 4; ++r) {
            const int row_l = wr * 64 + mi * 16 + quad * 4 + r;
            #pragma unroll
            for (int ni = 0; ni < 4; ++ni) {
                const int col_l = wc * 64 + ni * 16 + lc;
                float ee = __builtin_amdgcn_exp2f(acc[mi][ni][r] * LSE_SCALE);
                if (diag_tile && (row_l == col_l)) ee = 0.0f;   // -inf mask
                rs[mi][r] += ee;
            }
        }
    }

    // Butterfly across the 16 lanes of each quad (same rows, different cols).
    #pragma unroll
    for (int off = 1; off < 16; off <<= 1)
        #pragma unroll
        for (int mi = 0; mi < 4; ++mi)
            #pragma unroll
            for (int r = 0; r < 4; ++r)
                rs[mi][r] += __shfl_xor(rs[mi][r], off, 64);

    if (lc == 0) {
        #pragma unroll
        for (int mi = 0; mi < 4; ++mi)
            #pragma unroll
            for (int r = 0; r < 4; ++r)
                rowred[wr * 64 + mi * 16 + quad * 4 + r][wc] = rs[mi][r];
    }
    __syncthreads();
    if (t < 128)
        partial[(size_t)ct * TWO_B + (size_t)rt * 128 + t] =
            rowred[t][0] + rowred[t][1];
}

// ---------------------------------------------------------------------------
// Kernel 3: per-row sumexp reduction over 64 column tiles -> lse - pos term,
// block-reduced; one partial per block (deterministic, no atomics).
// Grid: 32 blocks x 256 threads, one row per thread.
// ---------------------------------------------------------------------------
__global__ __launch_bounds__(256) void lse_kernel(
    const float* __restrict__ partial, const float* __restrict__ pos,
    float* __restrict__ blocksum)
{
    const int t = threadIdx.x;
    const int row = blockIdx.x * 256 + t;
    float s = 0.0f;
    #pragma unroll 8
    for (int ctile = 0; ctile < 64; ++ctile)
        s += partial[(size_t)ctile * TWO_B + row];
    float term = logf(s) - pos[row & (BATCH - 1)];   // sim_ij == sim_ji

    #pragma unroll
    for (int off = 32; off > 0; off >>= 1)
        term += __shfl_down(term, off);
    __shared__ float wsum[4];
    if ((t & 63) == 0) wsum[t >> 6] = term;
    __syncthreads();
    if (t == 0)
        blocksum[blockIdx.x] = wsum[0] + wsum[1] + wsum[2] + wsum[3];
}

__global__ void final_kernel(const float* __restrict__ blocksum,
                             float* __restrict__ out)
{
    const int t = threadIdx.x;   // 64 threads
    float v = (t < 32) ? blocksum[t] : 0.0f;
    #pragma unroll
    for (int off = 32; off > 0; off >>= 1)
        v += __shfl_down(v, off);
    if (t == 0) out[0] = v * (1.0f / (float)TWO_B);
}

// ---------------------------------------------------------------------------
extern "C" void kernel_launch(void* const* d_in, const int* in_sizes, int n_in,
                              void* d_out, int out_size, void* d_ws, size_t ws_size,
                              hipStream_t stream)
{
    const float* p1 = (const float*)d_in[0];
    const float* p2 = (const float*)d_in[1];
    float* out = (float*)d_out;

    // Workspace layout (all fully rewritten every call; poison-safe):
    //   z        : 8192*512 bf16  = 8,388,608 B
    //   pos      : 4096 f32       =    16,384 B
    //   partial  : 64*8192 f32    = 2,097,152 B
    //   blocksum : 32 f32         =       128 B
    char* ws = (char*)d_ws;
    __hip_bfloat16* z  = (__hip_bfloat16*)ws;
    float* pos         = (float*)(ws + 8388608);
    float* partial     = (float*)(ws + 8388608 + 16384);
    float* blocksum    = (float*)(ws + 8388608 + 16384 + 2097152);

    norm_kernel<<<BATCH, 256, 0, stream>>>(p1, p2, z, pos);
    sim_kernel<<<dim3(64, 64), 256, 0, stream>>>(z, partial);
    lse_kernel<<<32, 256, 0, stream>>>(partial, pos, blocksum);
    final_kernel<<<1, 64, 0, stream>>>(blocksum, out);
}

// Round 2
// 148.286 us; speedup vs baseline: 1.0687x; 1.0687x over previous
//
#include <hip/hip_runtime.h>
#include <hip/hip_bf16.h>
#include <math.h>

// Problem constants
#define BATCH   4096
#define DIM     512
#define TWO_B   8192
#define INV_T   10.0f                       // 1/TEMP
#define LSE_SCALE 14.426950408889634f       // log2(e)/TEMP

typedef __attribute__((ext_vector_type(8)))  short bf16x8;   // 8 bf16 = 4 VGPRs
typedef __attribute__((ext_vector_type(16))) float floatx16; // 32x32 MFMA acc

#define AS1(p) ((__attribute__((address_space(1))) void*)(p))
#define AS3(p) ((__attribute__((address_space(3))) void*)(p))

// ---------------------------------------------------------------------------
// Kernel 1: L2-normalize pairs (row i of proj_1, row i of proj_2), write bf16
// z[2B][D], and compute positives pos[i] = cos(z_i, z_{i+B})/TEMP in fp32.
// ---------------------------------------------------------------------------
__global__ __launch_bounds__(256) void norm_kernel(
    const float* __restrict__ p1, const float* __restrict__ p2,
    __hip_bfloat16* __restrict__ z, float* __restrict__ pos)
{
    const int i = blockIdx.x;          // 0..4095
    const int t = threadIdx.x;         // 0..255
    const int wave = t >> 6, lane = t & 63;

    const float2 xv = ((const float2*)(p1 + (size_t)i * DIM))[t];
    const float2 yv = ((const float2*)(p2 + (size_t)i * DIM))[t];

    float sx = fmaf(xv.x, xv.x, xv.y * xv.y);
    float sy = fmaf(yv.x, yv.x, yv.y * yv.y);
    float sd = fmaf(xv.x, yv.x, xv.y * yv.y);

    #pragma unroll
    for (int off = 32; off > 0; off >>= 1) {
        sx += __shfl_down(sx, off);
        sy += __shfl_down(sy, off);
        sd += __shfl_down(sd, off);
    }

    __shared__ float red[3][4];
    if (lane == 0) { red[0][wave] = sx; red[1][wave] = sy; red[2][wave] = sd; }
    __syncthreads();
    sx = red[0][0] + red[0][1] + red[0][2] + red[0][3];
    sy = red[1][0] + red[1][1] + red[1][2] + red[1][3];
    sd = red[2][0] + red[2][1] + red[2][2] + red[2][3];

    const float rx = 1.0f / fmaxf(sqrtf(sx), 1e-12f);
    const float ry = 1.0f / fmaxf(sqrtf(sy), 1e-12f);

    __hip_bfloat162* zx = (__hip_bfloat162*)(z + (size_t)i * DIM);
    __hip_bfloat162* zy = (__hip_bfloat162*)(z + (size_t)(i + BATCH) * DIM);
    __hip_bfloat162 ax, ay;
    ax.x = __float2bfloat16(xv.x * rx); ax.y = __float2bfloat16(xv.y * rx);
    ay.x = __float2bfloat16(yv.x * ry); ay.y = __float2bfloat16(yv.y * ry);
    zx[t] = ax;
    zy[t] = ay;

    if (t == 0) pos[i] = sd * rx * ry * INV_T;
}

// ---------------------------------------------------------------------------
// Kernel 2: fused z@z^T tile GEMM, 32x32x16 bf16 MFMA, 128x128 tile, BK=32,
// global_load_lds width=16, XOR-swizzled LDS (conflict-free b128 frag reads),
// exp2 epilogue with diagonal mask + per-COLUMN partial sums (== row sums by
// exact symmetry of the bf16 MFMA matrix) -> partial[rt][col].
// Grid: (64 col-tiles, 64 row-tiles), 256 threads (4 waves, 2x2 wave grid,
// each wave 64x64 via 2x2 of 32x32).
//
// LDS layout: tile[128][32] bf16, stored as 16B chunks; physical chunk
// position = chunk ^ ((row>>1)&3). Staging permutes the *global source*
// per lane (dest must stay base+lane*16 per the global_load_lds HW rule).
// ---------------------------------------------------------------------------
__global__ __launch_bounds__(256) void sim_kernel(
    const __hip_bfloat16* __restrict__ z, float* __restrict__ partial)
{
    __shared__ __hip_bfloat16 As[128 * 32];    // 8 KB
    __shared__ __hip_bfloat16 Bs[128 * 32];    // 8 KB
    __shared__ float colred[128 * 5];          // 2.5 KB, stride 5 = no conflicts

    const int ct = blockIdx.x;                 // column tile
    const int rt = blockIdx.y;                 // row tile
    const int t = threadIdx.x;
    const int wave = t >> 6, lane = t & 63;
    const int wr = wave >> 1, wc = wave & 1;   // 2x2 wave grid, 64x64 each
    const int lrow  = lane & 31;               // m/n within a 32-tile
    const int lhalf = lane >> 5;               // k-chunk selector

    const __hip_bfloat16* Ag = z + (size_t)rt * 128 * DIM;
    const __hip_bfloat16* Bg = z + (size_t)ct * 128 * DIM;

    floatx16 acc[2][2];
    #pragma unroll
    for (int mi = 0; mi < 2; ++mi)
        #pragma unroll
        for (int ni = 0; ni < 2; ++ni)
            acc[mi][ni] = (floatx16)0.0f;

    for (int k0 = 0; k0 < DIM; k0 += 32) {
        __syncthreads();   // previous iter's ds_reads done before overwrite
        #pragma unroll
        for (int i = 0; i < 2; ++i) {
            const int idx = i * 256 + t;               // 16B-chunk index
            const int row = idx >> 2;                  // [128][32] tile row
            const int lch = (idx & 3) ^ ((row >> 1) & 3); // logical chunk
            __builtin_amdgcn_global_load_lds(AS1(Ag + (size_t)row * DIM + k0 + lch * 8),
                                             AS3(As + i * 2048 + wave * 512),
                                             16, 0, 0);
            __builtin_amdgcn_global_load_lds(AS1(Bg + (size_t)row * DIM + k0 + lch * 8),
                                             AS3(Bs + i * 2048 + wave * 512),
                                             16, 0, 0);
        }
        __syncthreads();

        // A-frag (32x32x16): lane holds A[m = lane&31][k = (lane>>5)*8 + j].
        bf16x8 af[2][2], bf[2][2];
        #pragma unroll
        for (int mi = 0; mi < 2; ++mi)
            #pragma unroll
            for (int ks = 0; ks < 2; ++ks) {
                const int ch = ks * 2 + lhalf;
                const int rowA = wr * 64 + mi * 32 + lrow;
                const int pcA = ch ^ ((rowA >> 1) & 3);
                af[mi][ks] = *(const bf16x8*)(As + rowA * 32 + pcA * 8);
                const int rowB = wc * 64 + mi * 32 + lrow;
                const int pcB = ch ^ ((rowB >> 1) & 3);
                bf[mi][ks] = *(const bf16x8*)(Bs + rowB * 32 + pcB * 8);
            }

        #pragma unroll
        for (int ks = 0; ks < 2; ++ks)
            #pragma unroll
            for (int mi = 0; mi < 2; ++mi)
                #pragma unroll
                for (int ni = 0; ni < 2; ++ni)
                    acc[mi][ni] = __builtin_amdgcn_mfma_f32_32x32x16_bf16(
                        af[mi][ks], bf[ni][ks], acc[mi][ni], 0, 0, 0);
    }

    // Epilogue. C/D layout (m74/m101): col = lane&31,
    // row = (reg&3) + 8*(reg>>2) + 4*(lane>>5), within each 32x32 tile.
    // exp(sim) is bitwise-symmetric -> column sums == row sums, and column
    // sums need NO cross-lane reduction over cols: just sum regs in-lane.
    float cs[2] = {0.0f, 0.0f};
    const bool diag_tile = (rt == ct);
    #pragma unroll
    for (int mi = 0; mi < 2; ++mi) {
        #pragma unroll
        for (int ni = 0; ni < 2; ++ni) {
            const int col_l = wc * 64 + ni * 32 + lrow;
            #pragma unroll
            for (int r = 0; r < 16; ++r) {
                const int row_l = wr * 64 + mi * 32 + lhalf * 4 + (r & 3) + 8 * (r >> 2);
                float ee = __builtin_amdgcn_exp2f(acc[mi][ni][r] * LSE_SCALE);
                if (diag_tile && (row_l == col_l)) ee = 0.0f;   // -inf mask
                cs[ni] += ee;
            }
        }
    }
    // Each lane covers 32 of the block's 128 rows for its 2 columns.
    // 4 slots per column: slot = wr*2 + lhalf. Stride-5 LDS = conflict-free.
    const int slot = wr * 2 + lhalf;
    #pragma unroll
    for (int ni = 0; ni < 2; ++ni)
        colred[(wc * 64 + ni * 32 + lrow) * 5 + slot] = cs[ni];
    __syncthreads();
    if (t < 128) {
        const float s = colred[t * 5 + 0] + colred[t * 5 + 1] +
                        colred[t * 5 + 2] + colred[t * 5 + 3];
        partial[(size_t)rt * TWO_B + (size_t)ct * 128 + t] = s;
    }
}

// ---------------------------------------------------------------------------
// Kernel 3: per-column sumexp reduction over 64 row tiles (== row sumexp by
// symmetry) -> lse - pos term, block-reduced, one partial per block.
// ---------------------------------------------------------------------------
__global__ __launch_bounds__(256) void lse_kernel(
    const float* __restrict__ partial, const float* __restrict__ pos,
    float* __restrict__ blocksum)
{
    const int t = threadIdx.x;
    const int row = blockIdx.x * 256 + t;
    float s = 0.0f;
    #pragma unroll 8
    for (int tile = 0; tile < 64; ++tile)
        s += partial[(size_t)tile * TWO_B + row];
    float term = logf(s) - pos[row & (BATCH - 1)];   // sim_ij == sim_ji

    #pragma unroll
    for (int off = 32; off > 0; off >>= 1)
        term += __shfl_down(term, off);
    __shared__ float wsum[4];
    if ((t & 63) == 0) wsum[t >> 6] = term;
    __syncthreads();
    if (t == 0)
        blocksum[blockIdx.x] = wsum[0] + wsum[1] + wsum[2] + wsum[3];
}

__global__ void final_kernel(const float* __restrict__ blocksum,
                             float* __restrict__ out)
{
    const int t = threadIdx.x;   // 64 threads
    float v = (t < 32) ? blocksum[t] : 0.0f;
    #pragma unroll
    for (int off = 32; off > 0; off >>= 1)
        v += __shfl_down(v, off);
    if (t == 0) out[0] = v * (1.0f / (float)TWO_B);
}

// ---------------------------------------------------------------------------
extern "C" void kernel_launch(void* const* d_in, const int* in_sizes, int n_in,
                              void* d_out, int out_size, void* d_ws, size_t ws_size,
                              hipStream_t stream)
{
    const float* p1 = (const float*)d_in[0];
    const float* p2 = (const float*)d_in[1];
    float* out = (float*)d_out;

    // Workspace layout (all fully rewritten every call; poison-safe):
    //   z        : 8192*512 bf16  = 8,388,608 B
    //   pos      : 4096 f32       =    16,384 B
    //   partial  : 64*8192 f32    = 2,097,152 B
    //   blocksum : 32 f32         =       128 B
    char* ws = (char*)d_ws;
    __hip_bfloat16* z  = (__hip_bfloat16*)ws;
    float* pos         = (float*)(ws + 8388608);
    float* partial     = (float*)(ws + 8388608 + 16384);
    float* blocksum    = (float*)(ws + 8388608 + 16384 + 2097152);

    norm_kernel<<<BATCH, 256, 0, stream>>>(p1, p2, z, pos);
    sim_kernel<<<dim3(64, 64), 256, 0, stream>>>(z, partial);
    lse_kernel<<<32, 256, 0, stream>>>(partial, pos, blocksum);
    final_kernel<<<1, 64, 0, stream>>>(blocksum, out);
}

// Round 3
// 119.967 us; speedup vs baseline: 1.3209x; 1.2361x over previous
//
#include <hip/hip_runtime.h>
#include <hip/hip_bf16.h>
#include <math.h>

// Problem constants
#define BATCH   4096
#define DIM     512
#define TWO_B   8192
#define INV_T   10.0f                       // 1/TEMP
#define LSE_SCALE 14.426950408889634f       // log2(e)/TEMP
#define NTILE   64                          // 8192 / 128
#define NTRI    2080                        // 64*65/2 upper-triangle tiles

typedef __attribute__((ext_vector_type(8)))  short bf16x8;   // 8 bf16 = 4 VGPRs
typedef __attribute__((ext_vector_type(16))) float floatx16; // 32x32 MFMA acc

#define AS1(p) ((__attribute__((address_space(1))) void*)(p))
#define AS3(p) ((__attribute__((address_space(3))) void*)(p))

// ---------------------------------------------------------------------------
// Kernel 1: L2-normalize pairs (row i of proj_1, row i of proj_2), write bf16
// z[2B][D], and compute positives pos[i] = cos(z_i, z_{i+B})/TEMP in fp32.
// ---------------------------------------------------------------------------
__global__ __launch_bounds__(256) void norm_kernel(
    const float* __restrict__ p1, const float* __restrict__ p2,
    __hip_bfloat16* __restrict__ z, float* __restrict__ pos)
{
    const int i = blockIdx.x;          // 0..4095
    const int t = threadIdx.x;         // 0..255
    const int wave = t >> 6, lane = t & 63;

    const float2 xv = ((const float2*)(p1 + (size_t)i * DIM))[t];
    const float2 yv = ((const float2*)(p2 + (size_t)i * DIM))[t];

    float sx = fmaf(xv.x, xv.x, xv.y * xv.y);
    float sy = fmaf(yv.x, yv.x, yv.y * yv.y);
    float sd = fmaf(xv.x, yv.x, xv.y * yv.y);

    #pragma unroll
    for (int off = 32; off > 0; off >>= 1) {
        sx += __shfl_down(sx, off);
        sy += __shfl_down(sy, off);
        sd += __shfl_down(sd, off);
    }

    __shared__ float red[3][4];
    if (lane == 0) { red[0][wave] = sx; red[1][wave] = sy; red[2][wave] = sd; }
    __syncthreads();
    sx = red[0][0] + red[0][1] + red[0][2] + red[0][3];
    sy = red[1][0] + red[1][1] + red[1][2] + red[1][3];
    sd = red[2][0] + red[2][1] + red[2][2] + red[2][3];

    const float rx = 1.0f / fmaxf(sqrtf(sx), 1e-12f);
    const float ry = 1.0f / fmaxf(sqrtf(sy), 1e-12f);

    __hip_bfloat162* zx = (__hip_bfloat162*)(z + (size_t)i * DIM);
    __hip_bfloat162* zy = (__hip_bfloat162*)(z + (size_t)(i + BATCH) * DIM);
    __hip_bfloat162 ax, ay;
    ax.x = __float2bfloat16(xv.x * rx); ax.y = __float2bfloat16(xv.y * rx);
    ay.x = __float2bfloat16(yv.x * ry); ay.y = __float2bfloat16(yv.y * ry);
    zx[t] = ax;
    zy[t] = ay;

    if (t == 0) pos[i] = sd * rx * ry * INV_T;
}

// ---------------------------------------------------------------------------
// Kernel 2: UPPER-TRIANGLE fused z@z^T tiles. 32x32x16 bf16 MFMA, 128x128
// tile, BK=32, global_load_lds width=16, XOR-swizzled LDS. Each tile (rt,ct),
// rt<=ct, emits exp-sums both ways:
//   colsum_j = sum_i P[i][j] -> partial[rt][ct*128+j]   (in-lane, free)
//   rowsum_i = sum_j P[i][j] -> partial[ct][rt*128+i]   (LDS transpose reduce)
// Diagonal tiles (P symmetric after masking): colsums only.
// Every partial[k][row] slot is written exactly once -> deterministic.
// Grid: 2080 blocks x 256 threads (4 waves, 2x2 wave grid of 64x64).
// ---------------------------------------------------------------------------
__global__ __launch_bounds__(256) void sim_kernel(
    const __hip_bfloat16* __restrict__ z, float* __restrict__ partial)
{
    // Shared memory, two aliased phases:
    //   K-loop : As[128*32] bf16 (8 KB) | Bs[128*32] bf16 (8 KB)
    //   epilogue: rowbuf[128][64] f32 (32 KB) | colred[128*5] f32 (2.5 KB)
    __shared__ float smem_f[8832];             // 35,328 B
    __hip_bfloat16* As = (__hip_bfloat16*)smem_f;
    __hip_bfloat16* Bs = As + 128 * 32;
    float* rowbuf = smem_f;                    // [128][64]
    float* colred = smem_f + 8192;             // [128*5]

    // --- triangular decode: blockIdx.x -> (rt, ct), rt <= ct --------------
    const int idx = blockIdx.x;
    int rt = (int)((129.0 - sqrt(16641.0 - 8.0 * (double)idx)) * 0.5);
    // fixups (S(rt) = 64*rt - rt*(rt-1)/2 is row start)
    while (64 * (rt + 1) - ((rt + 1) * rt) / 2 <= idx) ++rt;
    while (64 * rt - (rt * (rt - 1)) / 2 > idx) --rt;
    const int ct = rt + (idx - (64 * rt - (rt * (rt - 1)) / 2));

    const int t = threadIdx.x;
    const int wave = t >> 6, lane = t & 63;
    const int wr = wave >> 1, wc = wave & 1;   // 2x2 wave grid, 64x64 each
    const int lrow  = lane & 31;               // m/n within a 32-tile
    const int lhalf = lane >> 5;               // k-chunk selector

    const __hip_bfloat16* Ag = z + (size_t)rt * 128 * DIM;
    const __hip_bfloat16* Bg = z + (size_t)ct * 128 * DIM;

    floatx16 acc[2][2];
    #pragma unroll
    for (int mi = 0; mi < 2; ++mi)
        #pragma unroll
        for (int ni = 0; ni < 2; ++ni)
            acc[mi][ni] = (floatx16)0.0f;

    for (int k0 = 0; k0 < DIM; k0 += 32) {
        __syncthreads();   // previous iter's ds_reads done before overwrite
        #pragma unroll
        for (int i = 0; i < 2; ++i) {
            const int cidx = i * 256 + t;                 // 16B-chunk index
            const int row = cidx >> 2;                    // [128][32] tile row
            const int lch = (cidx & 3) ^ ((row >> 1) & 3); // logical chunk
            __builtin_amdgcn_global_load_lds(AS1(Ag + (size_t)row * DIM + k0 + lch * 8),
                                             AS3(As + i * 2048 + wave * 512),
                                             16, 0, 0);
            __builtin_amdgcn_global_load_lds(AS1(Bg + (size_t)row * DIM + k0 + lch * 8),
                                             AS3(Bs + i * 2048 + wave * 512),
                                             16, 0, 0);
        }
        __syncthreads();

        // A-frag (32x32x16): lane holds A[m = lane&31][k = (lane>>5)*8 + j].
        bf16x8 af[2][2], bf[2][2];
        #pragma unroll
        for (int mi = 0; mi < 2; ++mi)
            #pragma unroll
            for (int ks = 0; ks < 2; ++ks) {
                const int ch = ks * 2 + lhalf;
                const int rowA = wr * 64 + mi * 32 + lrow;
                const int pcA = ch ^ ((rowA >> 1) & 3);
                af[mi][ks] = *(const bf16x8*)(As + rowA * 32 + pcA * 8);
                const int rowB = wc * 64 + mi * 32 + lrow;
                const int pcB = ch ^ ((rowB >> 1) & 3);
                bf[mi][ks] = *(const bf16x8*)(Bs + rowB * 32 + pcB * 8);
            }

        #pragma unroll
        for (int ks = 0; ks < 2; ++ks)
            #pragma unroll
            for (int mi = 0; mi < 2; ++mi)
                #pragma unroll
                for (int ni = 0; ni < 2; ++ni)
                    acc[mi][ni] = __builtin_amdgcn_mfma_f32_32x32x16_bf16(
                        af[mi][ks], bf[ni][ks], acc[mi][ni], 0, 0, 0);
    }

    // --- epilogue ----------------------------------------------------------
    // C/D layout (m74/m101): col = lane&31,
    // row = (reg&3) + 8*(reg>>2) + 4*(lane>>5), within each 32x32 tile.
    const bool diag = (rt == ct);
    float cs[2] = {0.0f, 0.0f};     // per-column sums (cols this lane owns)
    float rw[2][16];                // per-row partials (sum over ni in-lane)
    #pragma unroll
    for (int mi = 0; mi < 2; ++mi)
        #pragma unroll
        for (int r = 0; r < 16; ++r)
            rw[mi][r] = 0.0f;

    #pragma unroll
    for (int mi = 0; mi < 2; ++mi) {
        #pragma unroll
        for (int ni = 0; ni < 2; ++ni) {
            const int col_l = wc * 64 + ni * 32 + lrow;
            #pragma unroll
            for (int r = 0; r < 16; ++r) {
                const int row_l = wr * 64 + mi * 32 + lhalf * 4 + (r & 3) + 8 * (r >> 2);
                float ee = __builtin_amdgcn_exp2f(acc[mi][ni][r] * LSE_SCALE);
                if (diag && (row_l == col_l)) ee = 0.0f;   // -inf self mask
                cs[ni] += ee;
                rw[mi][r] += ee;
            }
        }
    }

    __syncthreads();   // all K-loop ds_reads done before aliasing As/Bs

    // col sums -> colred (4 partials per column, stride-5 conflict-free)
    const int slot = wr * 2 + lhalf;
    #pragma unroll
    for (int ni = 0; ni < 2; ++ni)
        colred[(wc * 64 + ni * 32 + lrow) * 5 + slot] = cs[ni];

    // row partials -> rowbuf[row][wc*32 + lane31]
    if (!diag) {
        #pragma unroll
        for (int mi = 0; mi < 2; ++mi)
            #pragma unroll
            for (int r = 0; r < 16; ++r) {
                const int row_l = wr * 64 + mi * 32 + lhalf * 4 + (r & 3) + 8 * (r >> 2);
                rowbuf[row_l * 64 + wc * 32 + lrow] = rw[mi][r];
            }
    }
    __syncthreads();

    // colsum_j = row-sum of global row (ct*128+j) over cols in rt block
    if (t < 128) {
        const float s = colred[t * 5 + 0] + colred[t * 5 + 1] +
                        colred[t * 5 + 2] + colred[t * 5 + 3];
        partial[(size_t)rt * TWO_B + (size_t)ct * 128 + t] = s;
    }
    // rowsum_i = row-sum of global row (rt*128+i) over cols in ct block
    if (!diag) {
        const float4* rb = (const float4*)(rowbuf + (t >> 1) * 64 + (t & 1) * 32);
        float s = 0.0f;
        #pragma unroll
        for (int j = 0; j < 8; ++j) {
            const float4 v = rb[j];
            s += (v.x + v.y) + (v.z + v.w);
        }
        s += __shfl_xor(s, 1, 64);            // combine the two half-rows
        if ((t & 1) == 0)
            partial[(size_t)ct * TWO_B + (size_t)rt * 128 + (t >> 1)] = s;
    }
}

// ---------------------------------------------------------------------------
// Kernel 3: per-row sumexp over the 64 partial contributions -> lse - pos,
// block-reduced; one partial per block (deterministic, no atomics).
// ---------------------------------------------------------------------------
__global__ __launch_bounds__(256) void lse_kernel(
    const float* __restrict__ partial, const float* __restrict__ pos,
    float* __restrict__ blocksum)
{
    const int t = threadIdx.x;
    const int row = blockIdx.x * 256 + t;
    float s = 0.0f;
    #pragma unroll 8
    for (int tile = 0; tile < 64; ++tile)
        s += partial[(size_t)tile * TWO_B + row];
    float term = logf(s) - pos[row & (BATCH - 1)];   // sim_ij == sim_ji

    #pragma unroll
    for (int off = 32; off > 0; off >>= 1)
        term += __shfl_down(term, off);
    __shared__ float wsum[4];
    if ((t & 63) == 0) wsum[t >> 6] = term;
    __syncthreads();
    if (t == 0)
        blocksum[blockIdx.x] = wsum[0] + wsum[1] + wsum[2] + wsum[3];
}

__global__ void final_kernel(const float* __restrict__ blocksum,
                             float* __restrict__ out)
{
    const int t = threadIdx.x;   // 64 threads
    float v = (t < 32) ? blocksum[t] : 0.0f;
    #pragma unroll
    for (int off = 32; off > 0; off >>= 1)
        v += __shfl_down(v, off);
    if (t == 0) out[0] = v * (1.0f / (float)TWO_B);
}

// ---------------------------------------------------------------------------
extern "C" void kernel_launch(void* const* d_in, const int* in_sizes, int n_in,
                              void* d_out, int out_size, void* d_ws, size_t ws_size,
                              hipStream_t stream)
{
    const float* p1 = (const float*)d_in[0];
    const float* p2 = (const float*)d_in[1];
    float* out = (float*)d_out;

    // Workspace layout (all fully rewritten every call; poison-safe):
    //   z        : 8192*512 bf16  = 8,388,608 B
    //   pos      : 4096 f32       =    16,384 B
    //   partial  : 64*8192 f32    = 2,097,152 B
    //   blocksum : 32 f32         =       128 B
    char* ws = (char*)d_ws;
    __hip_bfloat16* z  = (__hip_bfloat16*)ws;
    float* pos         = (float*)(ws + 8388608);
    float* partial     = (float*)(ws + 8388608 + 16384);
    float* blocksum    = (float*)(ws + 8388608 + 16384 + 2097152);

    norm_kernel<<<BATCH, 256, 0, stream>>>(p1, p2, z, pos);
    sim_kernel<<<NTRI, 256, 0, stream>>>(z, partial);
    lse_kernel<<<32, 256, 0, stream>>>(partial, pos, blocksum);
    final_kernel<<<1, 64, 0, stream>>>(blocksum, out);
}